// Round 4
// baseline (534.207 us; speedup 1.0000x reference)
//
#include <hip/hip_runtime.h>
#include <math.h>

#define IFZ 256
#define KZ  16
#define AHZ 8
#define AFZ 32
#define HF  256   // AHZ*AFZ

typedef _Float16 half8 __attribute__((ext_vector_type(8)));
typedef _Float16 half4 __attribute__((ext_vector_type(4)));
typedef float    f32x4 __attribute__((ext_vector_type(4)));

#define FLAG_BIAS 1
#define FLAG_SIG  2
#define FLAG_ROPE 4
#define FLAG_F16  8

// ---------------------------------------------------------------------------
// f32 -> f16 vector convert (x1 -> x1h)
// ---------------------------------------------------------------------------
__global__ void conv_f16(const float* __restrict__ in, _Float16* __restrict__ out, int n4)
{
    int i = blockIdx.x * 256 + threadIdx.x;
    if (i >= n4) return;
    float4 v = reinterpret_cast<const float4*>(in)[i];
    half4 h;
    h[0] = (_Float16)v.x; h[1] = (_Float16)v.y;
    h[2] = (_Float16)v.z; h[3] = (_Float16)v.w;
    reinterpret_cast<half4*>(out)[i] = h;
}

// ---------------------------------------------------------------------------
// Weight transpose + convert: WT[m][c][k] = (f16) W_m[k][c]   (5 x 256x256)
// ---------------------------------------------------------------------------
__global__ void conv_wt(const float* __restrict__ w0, const float* __restrict__ w1,
                        const float* __restrict__ w2, const float* __restrict__ w3,
                        const float* __restrict__ w4, _Float16* __restrict__ out)
{
    int k = blockIdx.x;      // 0..255
    int m = blockIdx.y;      // 0..4
    int c = threadIdx.x;     // 0..255
    const float* w = (m == 0) ? w0 : (m == 1) ? w1 : (m == 2) ? w2 : (m == 3) ? w3 : w4;
    out[(size_t)m * 65536 + (size_t)c * 256 + k] = (_Float16)w[(size_t)k * 256 + c];
}

// ---------------------------------------------------------------------------
// MFMA GEMM: out[n][c] = epilogue( sum_k A[n][k] * W[k][c] )
// A: f16 [N][256] row-major. BT: f16 [256 cols][256 k] (W transposed).
// tile 64x64, 4 waves, mfma_f32_16x16x32_f16.
// ---------------------------------------------------------------------------
__launch_bounds__(256)
__global__ void gemm16(const _Float16* __restrict__ A, const _Float16* __restrict__ BT,
                       const float* __restrict__ bias, const float* __restrict__ pe,
                       void* __restrict__ out, int N, int flags)
{
    __shared__ _Float16 as[64][40];   // 64 rows x 32 k (+8 pad)
    __shared__ _Float16 bs[64][40];   // 64 cols x 32 k (+8 pad)

    const int tid = threadIdx.x;
    const int l   = tid & 63;
    const int w   = tid >> 6;
    const int n0  = blockIdx.x * 64;
    const int c0  = blockIdx.y * 64;

    f32x4 acc[4];
    #pragma unroll
    for (int b = 0; b < 4; ++b) { acc[b][0]=0.f; acc[b][1]=0.f; acc[b][2]=0.f; acc[b][3]=0.f; }

    const int srow = tid >> 2;         // 0..63
    const int sch  = (tid & 3) * 8;    // 0,8,16,24

    for (int kt = 0; kt < 8; ++kt) {
        const int k0 = kt * 32;
        half8 av{};
        if (n0 + srow < N)
            av = *reinterpret_cast<const half8*>(A + (size_t)(n0 + srow) * IFZ + k0 + sch);
        half8 bv = *reinterpret_cast<const half8*>(BT + (size_t)(c0 + srow) * IFZ + k0 + sch);
        __syncthreads();   // protect previous iteration's reads
        *reinterpret_cast<half8*>(&as[srow][sch]) = av;
        *reinterpret_cast<half8*>(&bs[srow][sch]) = bv;
        __syncthreads();

        half8 af = *reinterpret_cast<const half8*>(&as[16 * w + (l & 15)][8 * (l >> 4)]);
        #pragma unroll
        for (int b = 0; b < 4; ++b) {
            half8 bf = *reinterpret_cast<const half8*>(&bs[16 * b + (l & 15)][8 * (l >> 4)]);
            acc[b] = __builtin_amdgcn_mfma_f32_16x16x32_f16(af, bf, acc[b], 0, 0, 0);
        }
    }

    // C/D layout: col = c0 + 16b + (l&15), row = n0 + 16w + 4*(l>>4) + r
    #pragma unroll
    for (int r = 0; r < 4; ++r) {
        const int grow = n0 + 16 * w + ((l >> 4) << 2) + r;
        if (grow >= N) continue;
        if (flags & FLAG_ROPE) {
            #pragma unroll
            for (int pb = 0; pb < 4; pb += 2) {
                float a0 = pe[(size_t)grow * AFZ + (l & 15)];
                float a1 = pe[(size_t)grow * AFZ + 16 + (l & 15)];
                float s0, c0f, s1, c1f;
                __sincosf(a0, &s0, &c0f);
                __sincosf(a1, &s1, &c1f);
                float v0 = acc[pb][r], v1 = acc[pb + 1][r];
                float o0 = v0 * c0f - v1 * s0;   // f < 16: k[f]cos - k[f+16]sin
                float o1 = v1 * c1f + v0 * s1;   // f >=16: k[f]cos + k[f-16]sin
                _Float16* o = (_Float16*)out;
                o[(size_t)grow * HF + c0 + 16 * pb       + (l & 15)] = (_Float16)o0;
                o[(size_t)grow * HF + c0 + 16 * (pb + 1) + (l & 15)] = (_Float16)o1;
            }
        } else {
            #pragma unroll
            for (int b = 0; b < 4; ++b) {
                float v = acc[b][r];
                const int c = c0 + 16 * b + (l & 15);
                if (flags & FLAG_BIAS) v += bias[c];
                if (flags & FLAG_SIG)  v = 1.f / (1.f + __expf(-v));
                if (flags & FLAG_F16)  ((_Float16*)out)[(size_t)grow * HF + c] = (_Float16)v;
                else                   ((float*)out)[(size_t)grow * HF + c] = v;
            }
        }
    }
}

// ---------------------------------------------------------------------------
// bias2[row][h] = LN(x2[row]) @ Wb   (row = n*KZ+e)
// Each thread owns a QUARTER row (64 floats in registers) -> reductions are
// only 2 shfl levels (xor 1,2). 20 wave-shfls per 16 rows vs 60/row before.
// No LDS. HBM-bound stream of x2 (327 MB).
// ---------------------------------------------------------------------------
__launch_bounds__(256)
__global__ void bias2_kern(const float* __restrict__ x2, const float* __restrict__ g,
                           const float* __restrict__ b, const float* __restrict__ Wb,
                           float* __restrict__ out, int R)
{
    const int tid = threadIdx.x;
    const int row = blockIdx.x * 64 + (tid >> 2);   // global row (n*KZ+e)
    const int ch  = tid & 3;                        // quarter index
    if (row >= R) return;

    const float* xr = x2 + (size_t)row * IFZ + ch * 64;
    float4 xv[16];
    #pragma unroll
    for (int i = 0; i < 16; ++i)
        xv[i] = reinterpret_cast<const float4*>(xr)[i];

    float s = 0.f, q = 0.f;
    #pragma unroll
    for (int i = 0; i < 16; ++i) {
        s += xv[i].x + xv[i].y + xv[i].z + xv[i].w;
        q += xv[i].x*xv[i].x + xv[i].y*xv[i].y + xv[i].z*xv[i].z + xv[i].w*xv[i].w;
    }
    // combine across the 4 quarter-threads of this row (lanes l^1, l^2)
    s += __shfl_xor(s, 1); s += __shfl_xor(s, 2);
    q += __shfl_xor(q, 1); q += __shfl_xor(q, 2);
    const float m    = s * (1.f / 256.f);
    const float var  = q * (1.f / 256.f) - m * m;
    const float rstd = rsqrtf(var + 1e-5f);

    float ph[8] = {0,0,0,0,0,0,0,0};
    #pragma unroll
    for (int i = 0; i < 16; ++i) {
        float4 gv = reinterpret_cast<const float4*>(g + ch * 64)[i];
        float4 bv = reinterpret_cast<const float4*>(b + ch * 64)[i];
        float lnv[4];
        lnv[0] = (xv[i].x - m) * rstd * gv.x + bv.x;
        lnv[1] = (xv[i].y - m) * rstd * gv.y + bv.y;
        lnv[2] = (xv[i].z - m) * rstd * gv.z + bv.z;
        lnv[3] = (xv[i].w - m) * rstd * gv.w + bv.w;
        #pragma unroll
        for (int j = 0; j < 4; ++j) {
            const int f = ch * 64 + i * 4 + j;
            float4 w0 = *reinterpret_cast<const float4*>(Wb + (size_t)f * 8);
            float4 w1 = *reinterpret_cast<const float4*>(Wb + (size_t)f * 8 + 4);
            ph[0] = fmaf(lnv[j], w0.x, ph[0]); ph[1] = fmaf(lnv[j], w0.y, ph[1]);
            ph[2] = fmaf(lnv[j], w0.z, ph[2]); ph[3] = fmaf(lnv[j], w0.w, ph[3]);
            ph[4] = fmaf(lnv[j], w1.x, ph[4]); ph[5] = fmaf(lnv[j], w1.y, ph[5]);
            ph[6] = fmaf(lnv[j], w1.z, ph[6]); ph[7] = fmaf(lnv[j], w1.w, ph[7]);
        }
    }
    // combine head partials across the 4 quarter-threads (2 levels)
    #pragma unroll
    for (int h = 0; h < 8; ++h) {
        ph[h] += __shfl_xor(ph[h], 1);
        ph[h] += __shfl_xor(ph[h], 2);
    }
    // lane ch writes heads 2ch, 2ch+1 -> 32B contiguous per row across 4 lanes
    float2 o2 = { ph[2 * ch], ph[2 * ch + 1] };
    *reinterpret_cast<float2*>(out + (size_t)row * 8 + 2 * ch) = o2;
}

// ---------------------------------------------------------------------------
// Slim attention: gather roped-K/V (f16), scores + bias2, softmax, PV, gate
// ---------------------------------------------------------------------------
__launch_bounds__(256)
__global__ void attn_node(const _Float16* __restrict__ Qh, const _Float16* __restrict__ Kh,
                          const _Float16* __restrict__ Vh, const _Float16* __restrict__ Gh,
                          const int* __restrict__ eidx, const float* __restrict__ b2,
                          _Float16* __restrict__ AOh, int N)
{
    __shared__ float sc[KZ][9];
    __shared__ float wn[KZ][9];
    __shared__ float po[4][264];
    __shared__ int   eix[KZ];

    const int n   = blockIdx.x;
    const int tid = threadIdx.x;
    const int l   = tid & 63;
    const int w   = tid >> 6;

    if (tid < KZ) eix[tid] = eidx[(size_t)n * KZ + tid];
    __syncthreads();

    float q[4];
    {
        half4 qh = *reinterpret_cast<const half4*>(Qh + (size_t)n * HF + 4 * l);
        q[0] = (float)qh[0]; q[1] = (float)qh[1]; q[2] = (float)qh[2]; q[3] = (float)qh[3];
    }

    float kv[4][4], vv[4][4];
    #pragma unroll
    for (int e4 = 0; e4 < 4; ++e4) {
        const int row = eix[w * 4 + e4];
        half4 kh = *reinterpret_cast<const half4*>(Kh + (size_t)row * HF + 4 * l);
        half4 vh = *reinterpret_cast<const half4*>(Vh + (size_t)row * HF + 4 * l);
        #pragma unroll
        for (int i = 0; i < 4; ++i) { kv[e4][i] = (float)kh[i]; vv[e4][i] = (float)vh[i]; }
    }

    // scores: lane holds elems 4l..4l+3 (head h = l>>3); reduce over 8-lane head group
    #pragma unroll
    for (int e4 = 0; e4 < 4; ++e4) {
        float s = q[0]*kv[e4][0] + q[1]*kv[e4][1] + q[2]*kv[e4][2] + q[3]*kv[e4][3];
        s += __shfl_xor(s, 1); s += __shfl_xor(s, 2); s += __shfl_xor(s, 4);
        if ((l & 7) == 0) sc[w * 4 + e4][l >> 3] = s * 0.17677669529663687f;
    }
    __syncthreads();

    // softmax over e per head: 128 threads, (e,h) grid, 16-lane group reduce
    if (tid < 128) {
        const int e = l & 15;
        const int h = ((tid >> 6) << 2) + (l >> 4);
        float v = sc[e][h] + b2[((size_t)n * KZ + e) * AHZ + h];
        float m = v;
        m = fmaxf(m, __shfl_xor(m, 1)); m = fmaxf(m, __shfl_xor(m, 2));
        m = fmaxf(m, __shfl_xor(m, 4)); m = fmaxf(m, __shfl_xor(m, 8));
        float ex = __expf(v - m);
        float sum = ex;
        sum += __shfl_xor(sum, 1); sum += __shfl_xor(sum, 2);
        sum += __shfl_xor(sum, 4); sum += __shfl_xor(sum, 8);
        wn[e][h] = ex / sum;
    }
    __syncthreads();

    // PV partials per wave
    {
        const int h = l >> 3;
        float o[4] = {0.f, 0.f, 0.f, 0.f};
        #pragma unroll
        for (int e4 = 0; e4 < 4; ++e4) {
            const float we = wn[w * 4 + e4][h];
            #pragma unroll
            for (int i = 0; i < 4; ++i) o[i] = fmaf(we, vv[e4][i], o[i]);
        }
        float4 of = { o[0], o[1], o[2], o[3] };
        *reinterpret_cast<float4*>(&po[w][4 * l]) = of;
    }
    __syncthreads();

    // combine + gate + store f16
    if (tid < 64) {
        float4 r0 = *reinterpret_cast<const float4*>(&po[0][4 * l]);
        float4 r1 = *reinterpret_cast<const float4*>(&po[1][4 * l]);
        float4 r2 = *reinterpret_cast<const float4*>(&po[2][4 * l]);
        float4 r3 = *reinterpret_cast<const float4*>(&po[3][4 * l]);
        half4 gh = *reinterpret_cast<const half4*>(Gh + (size_t)n * HF + 4 * l);
        half4 oh;
        oh[0] = (_Float16)((r0.x + r1.x + r2.x + r3.x) * (float)gh[0]);
        oh[1] = (_Float16)((r0.y + r1.y + r2.y + r3.y) * (float)gh[1]);
        oh[2] = (_Float16)((r0.z + r1.z + r2.z + r3.z) * (float)gh[2]);
        oh[3] = (_Float16)((r0.w + r1.w + r2.w + r3.w) * (float)gh[3]);
        *reinterpret_cast<half4*>(AOh + (size_t)n * HF + 4 * l) = oh;
    }
}

// ---------------------------------------------------------------------------
// final: LN( RAW + sqrt(2)*x1 ) -> out     (one wave per row)
// ---------------------------------------------------------------------------
__launch_bounds__(256)
__global__ void final_ln(const float* __restrict__ RAWb,
                         const float* __restrict__ x1b,
                         const float* __restrict__ g1,
                         const float* __restrict__ b1,
                         float* __restrict__ outb,
                         int N)
{
    int n    = blockIdx.x * 4 + (threadIdx.x >> 6);
    int lane = threadIdx.x & 63;
    if (n >= N) return;
    const size_t off = (size_t)n * IFZ + lane * 4;
    float4 ur = *reinterpret_cast<const float4*>(RAWb + off);
    float4 ux = *reinterpret_cast<const float4*>(x1b + off);
    float x[4];
    x[0] = ur.x + 1.4142135623730951f * ux.x;
    x[1] = ur.y + 1.4142135623730951f * ux.y;
    x[2] = ur.z + 1.4142135623730951f * ux.z;
    x[3] = ur.w + 1.4142135623730951f * ux.w;
    float s = x[0] + x[1] + x[2] + x[3];
    float q = x[0]*x[0] + x[1]*x[1] + x[2]*x[2] + x[3]*x[3];
    #pragma unroll
    for (int o = 32; o > 0; o >>= 1) { s += __shfl_xor(s, o); q += __shfl_xor(q, o); }
    float m    = s * (1.f / 256.f);
    float var  = q * (1.f / 256.f) - m * m;
    float rstd = rsqrtf(var + 1e-5f);
    float4 uo;
    {
        int f = lane * 4;
        uo.x = (x[0] - m) * rstd * g1[f + 0] + b1[f + 0];
        uo.y = (x[1] - m) * rstd * g1[f + 1] + b1[f + 1];
        uo.z = (x[2] - m) * rstd * g1[f + 2] + b1[f + 2];
        uo.w = (x[3] - m) * rstd * g1[f + 3] + b1[f + 3];
    }
    *reinterpret_cast<float4*>(outb + off) = uo;
}

// ---------------------------------------------------------------------------
extern "C" void kernel_launch(void* const* d_in, const int* in_sizes, int n_in,
                              void* d_out, int out_size, void* d_ws, size_t ws_size,
                              hipStream_t stream)
{
    const float* x1   = (const float*)d_in[0];
    const float* x2   = (const float*)d_in[1];
    const float* pe   = (const float*)d_in[2];
    const int*   ei   = (const int*)d_in[3];
    const float* wq   = (const float*)d_in[4];
    const float* wk   = (const float*)d_in[5];
    const float* wv   = (const float*)d_in[6];
    const float* wb   = (const float*)d_in[7];
    const float* blng = (const float*)d_in[8];
    const float* blnb = (const float*)d_in[9];
    const float* wg   = (const float*)d_in[10];
    const float* bg   = (const float*)d_in[11];
    const float* wbk  = (const float*)d_in[12];
    const float* bbk  = (const float*)d_in[13];
    const float* g1   = (const float*)d_in[14];
    const float* b1   = (const float*)d_in[15];

    const int N = in_sizes[0] / IFZ;

    const size_t S2 = (((size_t)N * HF * 2) + 4095) & ~(size_t)4095;   // f16 buffer size
    char* base = (char*)d_ws;
    _Float16* X1H = (_Float16*)(base);
    _Float16* QH  = (_Float16*)(base + 1 * S2);
    _Float16* KH  = (_Float16*)(base + 2 * S2);
    _Float16* VH  = (_Float16*)(base + 3 * S2);
    _Float16* GH  = (_Float16*)(base + 4 * S2);
    float*    B2  = (float*)   (base + 5 * S2);     // N*KZ*8 f32 == S2 bytes
    _Float16* WT  = (_Float16*)(base + 6 * S2);     // 5 x 65536 f16
    _Float16* AOH = QH;                              // reuse: block n reads Q[n] then writes AO[n]
    float*    RAW = (float*)(base + 2 * S2);         // reuse KH+VH region (f32, 2*S2 bytes)

    // conversions
    conv_f16<<<dim3((N * IFZ / 4 + 255) / 256), 256, 0, stream>>>(x1, X1H, N * IFZ / 4);
    conv_wt<<<dim3(256, 5), 256, 0, stream>>>(wq, wk, wv, wg, wbk, WT);

    const int nt = (N + 63) / 64;
    // Q,K: rope'd f16; V: plain f16; G: sigmoid(x@Wg+bg) f16
    gemm16<<<dim3(nt, 4), 256, 0, stream>>>(X1H, WT,           nullptr, pe, QH, N, FLAG_ROPE | FLAG_F16);
    gemm16<<<dim3(nt, 4), 256, 0, stream>>>(X1H, WT + 65536,   nullptr, pe, KH, N, FLAG_ROPE | FLAG_F16);
    gemm16<<<dim3(nt, 4), 256, 0, stream>>>(X1H, WT + 131072,  nullptr, nullptr, VH, N, FLAG_F16);
    gemm16<<<dim3(nt, 4), 256, 0, stream>>>(X1H, WT + 196608,  bg,      nullptr, GH, N, FLAG_BIAS | FLAG_SIG | FLAG_F16);

    bias2_kern<<<dim3((N * KZ + 63) / 64), 256, 0, stream>>>(x2, blng, blnb, wb, B2, N * KZ);

    attn_node<<<dim3(N), 256, 0, stream>>>(QH, KH, VH, GH, ei, B2, AOH, N);

    gemm16<<<dim3(nt, 4), 256, 0, stream>>>(AOH, WT + 262144, bbk, nullptr, RAW, N, FLAG_BIAS);

    final_ln<<<dim3((N + 3) / 4), 256, 0, stream>>>(RAW, x1, g1, b1, (float*)d_out, N);
}

// Round 5
// 213.836 us; speedup vs baseline: 2.4982x; 2.4982x over previous
//
#include <hip/hip_runtime.h>
#include <math.h>

#define IFZ 256
#define KZ  16
#define AHZ 8
#define AFZ 32
#define HF  256   // AHZ*AFZ

typedef _Float16 half8 __attribute__((ext_vector_type(8)));
typedef _Float16 half4 __attribute__((ext_vector_type(4)));
typedef float    f32x4 __attribute__((ext_vector_type(4)));

#define FLAG_BIAS 1
#define FLAG_SIG  2
#define FLAG_ROPE 4
#define FLAG_F16  8

// ---------------------------------------------------------------------------
// f32 -> f16 vector convert (x1 -> x1h)
// ---------------------------------------------------------------------------
__global__ void conv_f16(const float* __restrict__ in, _Float16* __restrict__ out, int n4)
{
    int i = blockIdx.x * 256 + threadIdx.x;
    if (i >= n4) return;
    float4 v = reinterpret_cast<const float4*>(in)[i];
    half4 h;
    h[0] = (_Float16)v.x; h[1] = (_Float16)v.y;
    h[2] = (_Float16)v.z; h[3] = (_Float16)v.w;
    reinterpret_cast<half4*>(out)[i] = h;
}

// ---------------------------------------------------------------------------
// Weight transpose + convert: WT[m][c][k] = (f16) W_m[k][c]   (5 x 256x256)
// ---------------------------------------------------------------------------
__global__ void conv_wt(const float* __restrict__ w0, const float* __restrict__ w1,
                        const float* __restrict__ w2, const float* __restrict__ w3,
                        const float* __restrict__ w4, _Float16* __restrict__ out)
{
    int k = blockIdx.x;      // 0..255
    int m = blockIdx.y;      // 0..4
    int c = threadIdx.x;     // 0..255
    const float* w = (m == 0) ? w0 : (m == 1) ? w1 : (m == 2) ? w2 : (m == 3) ? w3 : w4;
    out[(size_t)m * 65536 + (size_t)c * 256 + k] = (_Float16)w[(size_t)k * 256 + c];
}

// ---------------------------------------------------------------------------
// prep: c1T[c][f] (f16, [16][256]): cols 0-7 = g[f]*Wb[f][c], col 8 = 1, rest 0
//       c23[0..7] = sum_f g*Wb ; c23[8..15] = sum_f b*Wb
// single block, 256 threads
// ---------------------------------------------------------------------------
__global__ void prep_c1(const float* __restrict__ g, const float* __restrict__ b,
                        const float* __restrict__ Wb,
                        _Float16* __restrict__ c1T, float* __restrict__ c23)
{
    __shared__ float red[4][16];
    const int f = threadIdx.x;      // 0..255
    const int w = f >> 6, l = f & 63;
    const float gv = g[f], bv = b[f];
    float ph2[8], ph3[8];
    #pragma unroll
    for (int h = 0; h < 8; ++h) {
        float wv = Wb[(size_t)f * 8 + h];
        c1T[h * 256 + f] = (_Float16)(gv * wv);
        ph2[h] = gv * wv;
        ph3[h] = bv * wv;
    }
    c1T[8 * 256 + f] = (_Float16)1.0f;
    #pragma unroll
    for (int cc = 9; cc < 16; ++cc) c1T[cc * 256 + f] = (_Float16)0.0f;

    #pragma unroll
    for (int h = 0; h < 8; ++h) {
        #pragma unroll
        for (int o = 32; o > 0; o >>= 1) {
            ph2[h] += __shfl_xor(ph2[h], o);
            ph3[h] += __shfl_xor(ph3[h], o);
        }
        if (l == h) { red[w][h] = ph2[h]; red[w][8 + h] = ph3[h]; }
    }
    __syncthreads();
    if (f < 16) c23[f] = red[0][f] + red[1][f] + red[2][f] + red[3][f];
}

// ---------------------------------------------------------------------------
// MFMA GEMM: out[n][c] = epilogue( sum_k A[n][k] * W[k][c] )
// ---------------------------------------------------------------------------
__launch_bounds__(256)
__global__ void gemm16(const _Float16* __restrict__ A, const _Float16* __restrict__ BT,
                       const float* __restrict__ bias, const float* __restrict__ pe,
                       void* __restrict__ out, int N, int flags)
{
    __shared__ _Float16 as[64][40];   // 64 rows x 32 k (+8 pad)
    __shared__ _Float16 bs[64][40];   // 64 cols x 32 k (+8 pad)

    const int tid = threadIdx.x;
    const int l   = tid & 63;
    const int w   = tid >> 6;
    const int n0  = blockIdx.x * 64;
    const int c0  = blockIdx.y * 64;

    f32x4 acc[4];
    #pragma unroll
    for (int b = 0; b < 4; ++b) { acc[b][0]=0.f; acc[b][1]=0.f; acc[b][2]=0.f; acc[b][3]=0.f; }

    const int srow = tid >> 2;         // 0..63
    const int sch  = (tid & 3) * 8;    // 0,8,16,24

    for (int kt = 0; kt < 8; ++kt) {
        const int k0 = kt * 32;
        half8 av{};
        if (n0 + srow < N)
            av = *reinterpret_cast<const half8*>(A + (size_t)(n0 + srow) * IFZ + k0 + sch);
        half8 bv = *reinterpret_cast<const half8*>(BT + (size_t)(c0 + srow) * IFZ + k0 + sch);
        __syncthreads();   // protect previous iteration's reads
        *reinterpret_cast<half8*>(&as[srow][sch]) = av;
        *reinterpret_cast<half8*>(&bs[srow][sch]) = bv;
        __syncthreads();

        half8 af = *reinterpret_cast<const half8*>(&as[16 * w + (l & 15)][8 * (l >> 4)]);
        #pragma unroll
        for (int b = 0; b < 4; ++b) {
            half8 bf = *reinterpret_cast<const half8*>(&bs[16 * b + (l & 15)][8 * (l >> 4)]);
            acc[b] = __builtin_amdgcn_mfma_f32_16x16x32_f16(af, bf, acc[b], 0, 0, 0);
        }
    }

    // C/D layout: col = c0 + 16b + (l&15), row = n0 + 16w + 4*(l>>4) + r
    #pragma unroll
    for (int r = 0; r < 4; ++r) {
        const int grow = n0 + 16 * w + ((l >> 4) << 2) + r;
        if (grow >= N) continue;
        if (flags & FLAG_ROPE) {
            #pragma unroll
            for (int pb = 0; pb < 4; pb += 2) {
                float a0 = pe[(size_t)grow * AFZ + (l & 15)];
                float a1 = pe[(size_t)grow * AFZ + 16 + (l & 15)];
                float s0, c0f, s1, c1f;
                __sincosf(a0, &s0, &c0f);
                __sincosf(a1, &s1, &c1f);
                float v0 = acc[pb][r], v1 = acc[pb + 1][r];
                float o0 = v0 * c0f - v1 * s0;   // f < 16: k[f]cos - k[f+16]sin
                float o1 = v1 * c1f + v0 * s1;   // f >=16: k[f]cos + k[f-16]sin
                _Float16* o = (_Float16*)out;
                o[(size_t)grow * HF + c0 + 16 * pb       + (l & 15)] = (_Float16)o0;
                o[(size_t)grow * HF + c0 + 16 * (pb + 1) + (l & 15)] = (_Float16)o1;
            }
        } else {
            #pragma unroll
            for (int b = 0; b < 4; ++b) {
                float v = acc[b][r];
                const int c = c0 + 16 * b + (l & 15);
                if (flags & FLAG_BIAS) v += bias[c];
                if (flags & FLAG_SIG)  v = 1.f / (1.f + __expf(-v));
                if (flags & FLAG_F16)  ((_Float16*)out)[(size_t)grow * HF + c] = (_Float16)v;
                else                   ((float*)out)[(size_t)grow * HF + c] = v;
            }
        }
    }
}

// ---------------------------------------------------------------------------
// bias2 via MFMA: per 16-row tile, C1 = [x]@[c1|1] gives P[h] (cols 0-7) and
// S1 (col 8); C2 = [x^2]@same gives S2 (col 8). Then
// bias2[r][h] = rstd*(P[h] - m*c2[h]) + c3[h]. Zero reduction shuffles;
// fully-coalesced x2 stream. One wave per 16 rows.
// ---------------------------------------------------------------------------
__launch_bounds__(256)
__global__ void bias2_mfma(const float* __restrict__ x2,
                           const _Float16* __restrict__ c1T,
                           const float* __restrict__ c23,
                           float* __restrict__ out, int R)
{
    const int tid = threadIdx.x;
    const int l = tid & 63;
    const int w = tid >> 6;
    const int c = l & 15;      // col: head h for c<8, sum-col at c=8
    const int p = l >> 4;      // k-chunk (A) / row-quad (C)

    const int R0 = (blockIdx.x * 4 + w) * 16;
    if (R0 >= R) return;

    // B fragments in registers: bf[kt] = c1T[c][32kt + 8p .. +7]  (L2-resident)
    half8 bf[8];
    #pragma unroll
    for (int kt = 0; kt < 8; ++kt)
        bf[kt] = *reinterpret_cast<const half8*>(c1T + (size_t)c * 256 + kt * 32 + p * 8);

    const int arow = (R0 + c < R) ? (R0 + c) : (R - 1);   // A row = l&15
    const float* xr = x2 + (size_t)arow * IFZ + p * 8;

    f32x4 acc1 = {0.f, 0.f, 0.f, 0.f};
    f32x4 acc2 = {0.f, 0.f, 0.f, 0.f};
    #pragma unroll
    for (int kt = 0; kt < 8; ++kt) {
        float4 xa = *reinterpret_cast<const float4*>(xr + kt * 32);
        float4 xb = *reinterpret_cast<const float4*>(xr + kt * 32 + 4);
        half8 ax, ax2;
        ax[0] = (_Float16)xa.x; ax[1] = (_Float16)xa.y;
        ax[2] = (_Float16)xa.z; ax[3] = (_Float16)xa.w;
        ax[4] = (_Float16)xb.x; ax[5] = (_Float16)xb.y;
        ax[6] = (_Float16)xb.z; ax[7] = (_Float16)xb.w;
        ax2[0] = (_Float16)(xa.x * xa.x); ax2[1] = (_Float16)(xa.y * xa.y);
        ax2[2] = (_Float16)(xa.z * xa.z); ax2[3] = (_Float16)(xa.w * xa.w);
        ax2[4] = (_Float16)(xb.x * xb.x); ax2[5] = (_Float16)(xb.y * xb.y);
        ax2[6] = (_Float16)(xb.z * xb.z); ax2[7] = (_Float16)(xb.w * xb.w);
        acc1 = __builtin_amdgcn_mfma_f32_16x16x32_f16(ax,  bf[kt], acc1, 0, 0, 0);
        acc2 = __builtin_amdgcn_mfma_f32_16x16x32_f16(ax2, bf[kt], acc2, 0, 0, 0);
    }

    const float c2v = (c < 8) ? c23[c]     : 0.f;
    const float c3v = (c < 8) ? c23[8 + c] : 0.f;
    const int srcl = (l & 48) | 8;     // col-8 lane of this row-quad group
    #pragma unroll
    for (int j = 0; j < 4; ++j) {
        float s1 = __shfl(acc1[j], srcl);
        float s2 = __shfl(acc2[j], srcl);
        float m    = s1 * (1.f / 256.f);
        float var  = s2 * (1.f / 256.f) - m * m;
        float rstd = rsqrtf(var + 1e-5f);
        const int row = R0 + 4 * p + j;
        if (c < 8 && row < R)
            out[(size_t)row * 8 + c] = rstd * (acc1[j] - m * c2v) + c3v;
    }
}

// ---------------------------------------------------------------------------
// Slim attention: gather roped-K/V (f16), scores + bias2, softmax, PV, gate
// ---------------------------------------------------------------------------
__launch_bounds__(256)
__global__ void attn_node(const _Float16* __restrict__ Qh, const _Float16* __restrict__ Kh,
                          const _Float16* __restrict__ Vh, const _Float16* __restrict__ Gh,
                          const int* __restrict__ eidx, const float* __restrict__ b2,
                          _Float16* __restrict__ AOh, int N)
{
    __shared__ float sc[KZ][9];
    __shared__ float wn[KZ][9];
    __shared__ float po[4][264];
    __shared__ int   eix[KZ];

    const int n   = blockIdx.x;
    const int tid = threadIdx.x;
    const int l   = tid & 63;
    const int w   = tid >> 6;

    if (tid < KZ) eix[tid] = eidx[(size_t)n * KZ + tid];
    __syncthreads();

    float q[4];
    {
        half4 qh = *reinterpret_cast<const half4*>(Qh + (size_t)n * HF + 4 * l);
        q[0] = (float)qh[0]; q[1] = (float)qh[1]; q[2] = (float)qh[2]; q[3] = (float)qh[3];
    }

    float kv[4][4], vv[4][4];
    #pragma unroll
    for (int e4 = 0; e4 < 4; ++e4) {
        const int row = eix[w * 4 + e4];
        half4 kh = *reinterpret_cast<const half4*>(Kh + (size_t)row * HF + 4 * l);
        half4 vh = *reinterpret_cast<const half4*>(Vh + (size_t)row * HF + 4 * l);
        #pragma unroll
        for (int i = 0; i < 4; ++i) { kv[e4][i] = (float)kh[i]; vv[e4][i] = (float)vh[i]; }
    }

    // scores: lane holds elems 4l..4l+3 (head h = l>>3); reduce over 8-lane head group
    #pragma unroll
    for (int e4 = 0; e4 < 4; ++e4) {
        float s = q[0]*kv[e4][0] + q[1]*kv[e4][1] + q[2]*kv[e4][2] + q[3]*kv[e4][3];
        s += __shfl_xor(s, 1); s += __shfl_xor(s, 2); s += __shfl_xor(s, 4);
        if ((l & 7) == 0) sc[w * 4 + e4][l >> 3] = s * 0.17677669529663687f;
    }
    __syncthreads();

    // softmax over e per head: 128 threads, (e,h) grid, 16-lane group reduce
    if (tid < 128) {
        const int e = l & 15;
        const int h = ((tid >> 6) << 2) + (l >> 4);
        float v = sc[e][h] + b2[((size_t)n * KZ + e) * AHZ + h];
        float m = v;
        m = fmaxf(m, __shfl_xor(m, 1)); m = fmaxf(m, __shfl_xor(m, 2));
        m = fmaxf(m, __shfl_xor(m, 4)); m = fmaxf(m, __shfl_xor(m, 8));
        float ex = __expf(v - m);
        float sum = ex;
        sum += __shfl_xor(sum, 1); sum += __shfl_xor(sum, 2);
        sum += __shfl_xor(sum, 4); sum += __shfl_xor(sum, 8);
        wn[e][h] = ex / sum;
    }
    __syncthreads();

    // PV partials per wave
    {
        const int h = l >> 3;
        float o[4] = {0.f, 0.f, 0.f, 0.f};
        #pragma unroll
        for (int e4 = 0; e4 < 4; ++e4) {
            const float we = wn[w * 4 + e4][h];
            #pragma unroll
            for (int i = 0; i < 4; ++i) o[i] = fmaf(we, vv[e4][i], o[i]);
        }
        float4 of = { o[0], o[1], o[2], o[3] };
        *reinterpret_cast<float4*>(&po[w][4 * l]) = of;
    }
    __syncthreads();

    // combine + gate + store f16
    if (tid < 64) {
        float4 r0 = *reinterpret_cast<const float4*>(&po[0][4 * l]);
        float4 r1 = *reinterpret_cast<const float4*>(&po[1][4 * l]);
        float4 r2 = *reinterpret_cast<const float4*>(&po[2][4 * l]);
        float4 r3 = *reinterpret_cast<const float4*>(&po[3][4 * l]);
        half4 gh = *reinterpret_cast<const half4*>(Gh + (size_t)n * HF + 4 * l);
        half4 oh;
        oh[0] = (_Float16)((r0.x + r1.x + r2.x + r3.x) * (float)gh[0]);
        oh[1] = (_Float16)((r0.y + r1.y + r2.y + r3.y) * (float)gh[1]);
        oh[2] = (_Float16)((r0.z + r1.z + r2.z + r3.z) * (float)gh[2]);
        oh[3] = (_Float16)((r0.w + r1.w + r2.w + r3.w) * (float)gh[3]);
        *reinterpret_cast<half4*>(AOh + (size_t)n * HF + 4 * l) = oh;
    }
}

// ---------------------------------------------------------------------------
// final: LN( RAW + sqrt(2)*x1 ) -> out     (one wave per row)
// ---------------------------------------------------------------------------
__launch_bounds__(256)
__global__ void final_ln(const float* __restrict__ RAWb,
                         const float* __restrict__ x1b,
                         const float* __restrict__ g1,
                         const float* __restrict__ b1,
                         float* __restrict__ outb,
                         int N)
{
    int n    = blockIdx.x * 4 + (threadIdx.x >> 6);
    int lane = threadIdx.x & 63;
    if (n >= N) return;
    const size_t off = (size_t)n * IFZ + lane * 4;
    float4 ur = *reinterpret_cast<const float4*>(RAWb + off);
    float4 ux = *reinterpret_cast<const float4*>(x1b + off);
    float x[4];
    x[0] = ur.x + 1.4142135623730951f * ux.x;
    x[1] = ur.y + 1.4142135623730951f * ux.y;
    x[2] = ur.z + 1.4142135623730951f * ux.z;
    x[3] = ur.w + 1.4142135623730951f * ux.w;
    float s = x[0] + x[1] + x[2] + x[3];
    float q = x[0]*x[0] + x[1]*x[1] + x[2]*x[2] + x[3]*x[3];
    #pragma unroll
    for (int o = 32; o > 0; o >>= 1) { s += __shfl_xor(s, o); q += __shfl_xor(q, o); }
    float m    = s * (1.f / 256.f);
    float var  = q * (1.f / 256.f) - m * m;
    float rstd = rsqrtf(var + 1e-5f);
    float4 uo;
    {
        int f = lane * 4;
        uo.x = (x[0] - m) * rstd * g1[f + 0] + b1[f + 0];
        uo.y = (x[1] - m) * rstd * g1[f + 1] + b1[f + 1];
        uo.z = (x[2] - m) * rstd * g1[f + 2] + b1[f + 2];
        uo.w = (x[3] - m) * rstd * g1[f + 3] + b1[f + 3];
    }
    *reinterpret_cast<float4*>(outb + off) = uo;
}

// ---------------------------------------------------------------------------
extern "C" void kernel_launch(void* const* d_in, const int* in_sizes, int n_in,
                              void* d_out, int out_size, void* d_ws, size_t ws_size,
                              hipStream_t stream)
{
    const float* x1   = (const float*)d_in[0];
    const float* x2   = (const float*)d_in[1];
    const float* pe   = (const float*)d_in[2];
    const int*   ei   = (const int*)d_in[3];
    const float* wq   = (const float*)d_in[4];
    const float* wk   = (const float*)d_in[5];
    const float* wv   = (const float*)d_in[6];
    const float* wb   = (const float*)d_in[7];
    const float* blng = (const float*)d_in[8];
    const float* blnb = (const float*)d_in[9];
    const float* wg   = (const float*)d_in[10];
    const float* bg   = (const float*)d_in[11];
    const float* wbk  = (const float*)d_in[12];
    const float* bbk  = (const float*)d_in[13];
    const float* g1   = (const float*)d_in[14];
    const float* b1   = (const float*)d_in[15];

    const int N = in_sizes[0] / IFZ;

    const size_t S2 = (((size_t)N * HF * 2) + 4095) & ~(size_t)4095;   // f16 buffer size
    char* base = (char*)d_ws;
    _Float16* X1H = (_Float16*)(base);
    _Float16* QH  = (_Float16*)(base + 1 * S2);
    _Float16* KH  = (_Float16*)(base + 2 * S2);
    _Float16* VH  = (_Float16*)(base + 3 * S2);
    _Float16* GH  = (_Float16*)(base + 4 * S2);
    float*    B2  = (float*)   (base + 5 * S2);     // N*KZ*8 f32 == S2 bytes
    _Float16* WT  = (_Float16*)(base + 6 * S2);     // 5 x 65536 f16 (640KB)
    _Float16* C1T = (_Float16*)(base + 6 * S2 + (1u << 20));   // 16x256 f16
    float*    C23 = (float*)   (base + 6 * S2 + (1u << 20) + 8192);
    _Float16* AOH = QH;                              // reuse: block n reads Q[n] then writes AO[n]
    float*    RAW = (float*)(base + 2 * S2);         // reuse KH+VH region (f32, 2*S2 bytes)

    // conversions + prep
    conv_f16<<<dim3((N * IFZ / 4 + 255) / 256), 256, 0, stream>>>(x1, X1H, N * IFZ / 4);
    conv_wt<<<dim3(256, 5), 256, 0, stream>>>(wq, wk, wv, wg, wbk, WT);
    prep_c1<<<dim3(1), 256, 0, stream>>>(blng, blnb, wb, C1T, C23);

    const int nt = (N + 63) / 64;
    // Q,K: rope'd f16; V: plain f16; G: sigmoid(x@Wg+bg) f16
    gemm16<<<dim3(nt, 4), 256, 0, stream>>>(X1H, WT,           nullptr, pe, QH, N, FLAG_ROPE | FLAG_F16);
    gemm16<<<dim3(nt, 4), 256, 0, stream>>>(X1H, WT + 65536,   nullptr, pe, KH, N, FLAG_ROPE | FLAG_F16);
    gemm16<<<dim3(nt, 4), 256, 0, stream>>>(X1H, WT + 131072,  nullptr, nullptr, VH, N, FLAG_F16);
    gemm16<<<dim3(nt, 4), 256, 0, stream>>>(X1H, WT + 196608,  bg,      nullptr, GH, N, FLAG_BIAS | FLAG_SIG | FLAG_F16);

    const int R = N * KZ;
    bias2_mfma<<<dim3((R + 63) / 64), 256, 0, stream>>>(x2, C1T, C23, B2, R);

    attn_node<<<dim3(N), 256, 0, stream>>>(QH, KH, VH, GH, ei, B2, AOH, N);

    gemm16<<<dim3(nt, 4), 256, 0, stream>>>(AOH, WT + 262144, bbk, nullptr, RAW, N, FLAG_BIAS);

    final_ln<<<dim3((N + 3) / 4), 256, 0, stream>>>(RAW, x1, g1, b1, (float*)d_out, N);
}